// Round 1
// baseline (1364.221 us; speedup 1.0000x reference)
//
#include <hip/hip_runtime.h>

#define N_NODES 50000
#define N_EDGES 800000
#define D 128
#define BN_EPS 1e-5f

// ---------------- CSR construction ----------------

__global__ void count_deg(const int* __restrict__ dst, int* __restrict__ degi) {
    int e = blockIdx.x * 256 + threadIdx.x;
    if (e < N_EDGES) atomicAdd(&degi[dst[e]], 1);
}

__global__ void calc_inv(const int* __restrict__ degi, float* __restrict__ inv_deg) {
    int n = blockIdx.x * 256 + threadIdx.x;
    if (n < N_NODES) inv_deg[n] = 1.0f / (float)max(degi[n], 1);
}

__global__ void scan1(const int* __restrict__ degi, int* __restrict__ bsum) {
    __shared__ int s[256];
    int t = threadIdx.x, i = blockIdx.x * 256 + t;
    s[t] = (i < N_NODES) ? degi[i] : 0;
    __syncthreads();
    for (int off = 128; off > 0; off >>= 1) {
        if (t < off) s[t] += s[t + off];
        __syncthreads();
    }
    if (t == 0) bsum[blockIdx.x] = s[0];
}

__global__ void scan2(int* __restrict__ bsum, int nb) {
    __shared__ int s[256];
    int t = threadIdx.x;
    int v = (t < nb) ? bsum[t] : 0;
    s[t] = v;
    __syncthreads();
    for (int off = 1; off < 256; off <<= 1) {
        int x = (t >= off) ? s[t - off] : 0;
        __syncthreads();
        s[t] += x;
        __syncthreads();
    }
    if (t < nb) bsum[t] = s[t] - v;  // exclusive prefix of block sums
}

__global__ void scan3(const int* __restrict__ degi, const int* __restrict__ bsum,
                      int* __restrict__ offsets, int* __restrict__ cursor) {
    __shared__ int s[256];
    int t = threadIdx.x, i = blockIdx.x * 256 + t;
    int v = (i < N_NODES) ? degi[i] : 0;
    s[t] = v;
    __syncthreads();
    for (int off = 1; off < 256; off <<= 1) {
        int x = (t >= off) ? s[t - off] : 0;
        __syncthreads();
        s[t] += x;
        __syncthreads();
    }
    int excl = s[t] - v + bsum[blockIdx.x];
    if (i < N_NODES) { offsets[i] = excl; cursor[i] = excl; }
}

__global__ void csr_fill(const int* __restrict__ src, const int* __restrict__ dst,
                         int* __restrict__ cursor, int* __restrict__ csr) {
    int e = blockIdx.x * 256 + threadIdx.x;
    if (e < N_EDGES) {
        int p = atomicAdd(&cursor[dst[e]], 1);
        csr[p] = src[e];
    }
}

// ---------------- mean aggregation (gather, no atomics) ----------------
// 8 nodes per 256-thread block; 32 lanes per node, one float4 per lane.

__global__ void aggregate(const float* __restrict__ h, const int* __restrict__ csr,
                          const int* __restrict__ offsets, const int* __restrict__ degi,
                          const float* __restrict__ inv_deg, float* __restrict__ mean) {
    int node = blockIdx.x * 8 + (threadIdx.x >> 5);
    if (node >= N_NODES) return;
    int c = threadIdx.x & 31;
    int beg = offsets[node], n = degi[node];
    float ax = 0.f, ay = 0.f, az = 0.f, aw = 0.f;
    for (int i = 0; i < n; i++) {
        int s = csr[beg + i];
        float4 v = ((const float4*)h)[s * 32 + c];
        ax += v.x; ay += v.y; az += v.z; aw += v.w;
    }
    float w = inv_deg[node];
    float4 o; o.x = ax * w; o.y = ay * w; o.z = az * w; o.w = aw * w;
    ((float4*)mean)[node * 32 + c] = o;
}

// ---------------- fused SAGE GEMM: out = h@Ws + mean@Wn + b ----------------
// 32 rows x 128 cols per block; K chunked by 32; weights in LDS.
// In-place safe: each output row depends only on its own input row + mean buf.

__global__ __launch_bounds__(256) void sage_gemm(
    const float* __restrict__ h, const float* __restrict__ mean,
    const float* __restrict__ Ws, const float* __restrict__ Wn,
    const float* __restrict__ bias, float* __restrict__ out) {
    __shared__ float sWs[32][128];
    __shared__ float sWn[32][128];
    __shared__ float4 sA[32][8];
    __shared__ float4 sM[32][8];

    int t = threadIdx.x;
    int j = t & 127;
    int rh = t >> 7;  // 0/1
    int row0 = blockIdx.x * 32;

    float acc[16];
#pragma unroll
    for (int i = 0; i < 16; i++) acc[i] = 0.f;

    for (int k0 = 0; k0 < 128; k0 += 32) {
        __syncthreads();
        // stage weight chunks: 32x128 each
#pragma unroll
        for (int i = 0; i < 16; i++) {
            int idx = t + i * 256;
            int kk = idx >> 7, jj = idx & 127;
            sWs[kk][jj] = Ws[(k0 + kk) * 128 + jj];
            sWn[kk][jj] = Wn[(k0 + kk) * 128 + jj];
        }
        // stage A tiles: 32 rows x 32 k  (one float4 per thread per matrix)
        {
            int r = t >> 3, kq = t & 7;
            int rs = row0 + r;
            if (rs >= N_NODES) rs = N_NODES - 1;  // clamp (guarded on write)
            sA[r][kq] = ((const float4*)(h + (size_t)rs * D + k0))[kq];
            sM[r][kq] = ((const float4*)(mean + (size_t)rs * D + k0))[kq];
        }
        __syncthreads();

#pragma unroll
        for (int kq = 0; kq < 8; kq++) {
            float ws0 = sWs[kq * 4 + 0][j], ws1 = sWs[kq * 4 + 1][j];
            float ws2 = sWs[kq * 4 + 2][j], ws3 = sWs[kq * 4 + 3][j];
            float wn0 = sWn[kq * 4 + 0][j], wn1 = sWn[kq * 4 + 1][j];
            float wn2 = sWn[kq * 4 + 2][j], wn3 = sWn[kq * 4 + 3][j];
#pragma unroll
            for (int rr = 0; rr < 16; rr++) {
                int r = rh + rr * 2;
                float4 a = sA[r][kq];
                float4 m = sM[r][kq];
                acc[rr] += a.x * ws0 + a.y * ws1 + a.z * ws2 + a.w * ws3
                         + m.x * wn0 + m.y * wn1 + m.z * wn2 + m.w * wn3;
            }
        }
    }

    float bj = bias[j];
#pragma unroll
    for (int rr = 0; rr < 16; rr++) {
        int r = row0 + rh + rr * 2;
        if (r < N_NODES) out[(size_t)r * D + j] = acc[rr] + bj;
    }
}

// ---------------- BatchNorm stats + normalize+ReLU ----------------

__global__ void col_stats(const float* __restrict__ h, float* __restrict__ colsum,
                          float* __restrict__ colsumsq) {
    __shared__ float s1[256], s2[256];
    int t = threadIdx.x;
    int j = t & 127, half = t >> 7;
    float s = 0.f, q = 0.f;
    for (int r = blockIdx.x * 2 + half; r < N_NODES; r += gridDim.x * 2) {
        float v = h[(size_t)r * D + j];
        s += v; q += v * v;
    }
    s1[t] = s; s2[t] = q;
    __syncthreads();
    if (t < 128) {
        s = s1[t] + s1[t + 128];
        q = s2[t] + s2[t + 128];
        atomicAdd(&colsum[j], s);
        atomicAdd(&colsumsq[j], q);
    }
}

__global__ void bn_relu(float* __restrict__ h, const float* __restrict__ colsum,
                        const float* __restrict__ colsumsq,
                        const float* __restrict__ gamma, const float* __restrict__ beta) {
    int idx = blockIdx.x * 256 + threadIdx.x;  // over N*D/4 float4s
    if (idx >= N_NODES * (D / 4)) return;
    int c = idx & 31;
    float4 v = ((float4*)h)[idx];
    float4 s = ((const float4*)colsum)[c];
    float4 q = ((const float4*)colsumsq)[c];
    float4 g = ((const float4*)gamma)[c];
    float4 b = ((const float4*)beta)[c];
    const float invN = 1.0f / (float)N_NODES;
    float m, var, sc;
    m = s.x * invN; var = q.x * invN - m * m; sc = rsqrtf(var + BN_EPS) * g.x;
    v.x = fmaxf((v.x - m) * sc + b.x, 0.f);
    m = s.y * invN; var = q.y * invN - m * m; sc = rsqrtf(var + BN_EPS) * g.y;
    v.y = fmaxf((v.y - m) * sc + b.y, 0.f);
    m = s.z * invN; var = q.z * invN - m * m; sc = rsqrtf(var + BN_EPS) * g.z;
    v.z = fmaxf((v.z - m) * sc + b.z, 0.f);
    m = s.w * invN; var = q.w * invN - m * m; sc = rsqrtf(var + BN_EPS) * g.w;
    v.w = fmaxf((v.w - m) * sc + b.w, 0.f);
    ((float4*)h)[idx] = v;
}

// ---------------- launch ----------------

extern "C" void kernel_launch(void* const* d_in, const int* in_sizes, int n_in,
                              void* d_out, int out_size, void* d_ws, size_t ws_size,
                              hipStream_t stream) {
    const float* x   = (const float*)d_in[0];
    const int* src   = (const int*)d_in[1];
    const int* dst   = (const int*)d_in[2];
    const float* Ws0 = (const float*)d_in[3];
    const float* Wn0 = (const float*)d_in[4];
    const float* b0  = (const float*)d_in[5];
    const float* Ws1 = (const float*)d_in[6];
    const float* Wn1 = (const float*)d_in[7];
    const float* b1  = (const float*)d_in[8];
    const float* Ws2 = (const float*)d_in[9];
    const float* Wn2 = (const float*)d_in[10];
    const float* b2  = (const float*)d_in[11];
    const float* g0  = (const float*)d_in[12];
    const float* be0 = (const float*)d_in[13];
    const float* g1  = (const float*)d_in[14];
    const float* be1 = (const float*)d_in[15];

    char* base = (char*)d_ws;
    size_t NND = (size_t)N_NODES * D;
    float* meanbuf = (float*)base;                       // 25.6 MB
    float* bufH    = (float*)(base + NND * 4);           // 25.6 MB
    char* p = base + 2 * NND * 4;
    int* degi    = (int*)p;              p += N_NODES * 4;
    int* offsets = (int*)p;              p += N_NODES * 4;
    int* cursor  = (int*)p;              p += N_NODES * 4;
    int* csr     = (int*)p;              p += (size_t)N_EDGES * 4;
    int* bsum    = (int*)p;              p += 1024;
    float* colsum   = (float*)p;         p += 512;
    float* colsumsq = (float*)p;         p += 512;
    float* inv_deg  = (float*)p;         p += N_NODES * 4;

    const int NB = (N_NODES + 255) / 256;  // 196
    const int EB = (N_EDGES + 255) / 256;  // 3125

    // CSR build (once; reused by all 3 layers)
    hipMemsetAsync(degi, 0, N_NODES * 4, stream);
    count_deg<<<EB, 256, 0, stream>>>(dst, degi);
    calc_inv<<<NB, 256, 0, stream>>>(degi, inv_deg);
    scan1<<<NB, 256, 0, stream>>>(degi, bsum);
    scan2<<<1, 256, 0, stream>>>(bsum, NB);
    scan3<<<NB, 256, 0, stream>>>(degi, bsum, offsets, cursor);
    csr_fill<<<EB, 256, 0, stream>>>(src, dst, cursor, csr);

    const int AGG_B = (N_NODES + 7) / 8;       // 6250
    const int GEMM_B = (N_NODES + 31) / 32;    // 1563
    const int EW_B = (N_NODES * (D / 4) + 255) / 256;  // 6250

    // Layer 0: x -> bufH, then BN+ReLU in place
    aggregate<<<AGG_B, 256, 0, stream>>>(x, csr, offsets, degi, inv_deg, meanbuf);
    sage_gemm<<<GEMM_B, 256, 0, stream>>>(x, meanbuf, Ws0, Wn0, b0, bufH);
    hipMemsetAsync(colsum, 0, 1024, stream);  // colsum + colsumsq contiguous
    col_stats<<<256, 256, 0, stream>>>(bufH, colsum, colsumsq);
    bn_relu<<<EW_B, 256, 0, stream>>>(bufH, colsum, colsumsq, g0, be0);

    // Layer 1: bufH -> bufH (in place), BN+ReLU
    aggregate<<<AGG_B, 256, 0, stream>>>(bufH, csr, offsets, degi, inv_deg, meanbuf);
    sage_gemm<<<GEMM_B, 256, 0, stream>>>(bufH, meanbuf, Ws1, Wn1, b1, bufH);
    hipMemsetAsync(colsum, 0, 1024, stream);
    col_stats<<<256, 256, 0, stream>>>(bufH, colsum, colsumsq);
    bn_relu<<<EW_B, 256, 0, stream>>>(bufH, colsum, colsumsq, g1, be1);

    // Layer 2: bufH -> d_out (no BN)
    float* out = (float*)d_out;
    aggregate<<<AGG_B, 256, 0, stream>>>(bufH, csr, offsets, degi, inv_deg, meanbuf);
    sage_gemm<<<GEMM_B, 256, 0, stream>>>(bufH, meanbuf, Ws2, Wn2, b2, out);
}

// Round 2
// 632.808 us; speedup vs baseline: 2.1558x; 2.1558x over previous
//
#include <hip/hip_runtime.h>

#define N_NODES 50000
#define N_EDGES 800000
#define D 128
#define BN_EPS 1e-5f

// ---------------- CSR construction ----------------

__global__ void count_deg(const int* __restrict__ dst, int* __restrict__ degi) {
    int e = blockIdx.x * 256 + threadIdx.x;
    if (e < N_EDGES) atomicAdd(&degi[dst[e]], 1);
}

__global__ void calc_inv(const int* __restrict__ degi, float* __restrict__ inv_deg) {
    int n = blockIdx.x * 256 + threadIdx.x;
    if (n < N_NODES) inv_deg[n] = 1.0f / (float)max(degi[n], 1);
}

__global__ void scan1(const int* __restrict__ degi, int* __restrict__ bsum) {
    __shared__ int s[256];
    int t = threadIdx.x, i = blockIdx.x * 256 + t;
    s[t] = (i < N_NODES) ? degi[i] : 0;
    __syncthreads();
    for (int off = 128; off > 0; off >>= 1) {
        if (t < off) s[t] += s[t + off];
        __syncthreads();
    }
    if (t == 0) bsum[blockIdx.x] = s[0];
}

__global__ void scan2(int* __restrict__ bsum, int nb) {
    __shared__ int s[256];
    int t = threadIdx.x;
    int v = (t < nb) ? bsum[t] : 0;
    s[t] = v;
    __syncthreads();
    for (int off = 1; off < 256; off <<= 1) {
        int x = (t >= off) ? s[t - off] : 0;
        __syncthreads();
        s[t] += x;
        __syncthreads();
    }
    if (t < nb) bsum[t] = s[t] - v;  // exclusive prefix of block sums
}

__global__ void scan3(const int* __restrict__ degi, const int* __restrict__ bsum,
                      int* __restrict__ offsets, int* __restrict__ cursor) {
    __shared__ int s[256];
    int t = threadIdx.x, i = blockIdx.x * 256 + t;
    int v = (i < N_NODES) ? degi[i] : 0;
    s[t] = v;
    __syncthreads();
    for (int off = 1; off < 256; off <<= 1) {
        int x = (t >= off) ? s[t - off] : 0;
        __syncthreads();
        s[t] += x;
        __syncthreads();
    }
    int excl = s[t] - v + bsum[blockIdx.x];
    if (i < N_NODES) { offsets[i] = excl; cursor[i] = excl; }
}

__global__ void csr_fill(const int* __restrict__ src, const int* __restrict__ dst,
                         int* __restrict__ cursor, int* __restrict__ csr) {
    int e = blockIdx.x * 256 + threadIdx.x;
    if (e < N_EDGES) {
        int p = atomicAdd(&cursor[dst[e]], 1);
        csr[p] = src[e];
    }
}

// ---------------- mean aggregation (gather, no atomics) ----------------
// 8 nodes per 256-thread block; 32 lanes per node, one float4 per lane.

__global__ void aggregate(const float* __restrict__ h, const int* __restrict__ csr,
                          const int* __restrict__ offsets, const int* __restrict__ degi,
                          const float* __restrict__ inv_deg, float* __restrict__ mean) {
    int node = blockIdx.x * 8 + (threadIdx.x >> 5);
    if (node >= N_NODES) return;
    int c = threadIdx.x & 31;
    int beg = offsets[node], n = degi[node];
    float ax = 0.f, ay = 0.f, az = 0.f, aw = 0.f;
    for (int i = 0; i < n; i++) {
        int s = csr[beg + i];
        float4 v = ((const float4*)h)[s * 32 + c];
        ax += v.x; ay += v.y; az += v.z; aw += v.w;
    }
    float w = inv_deg[node];
    float4 o; o.x = ax * w; o.y = ay * w; o.z = az * w; o.w = aw * w;
    ((float4*)mean)[node * 32 + c] = o;
}

// ---------------- fused SAGE GEMM: out = [h|mean] @ [Ws;Wn] + b ----------------
// Single logical K=256 GEMM. Block = 64 rows x 128 cols, 256 threads,
// 8x4 register tile per thread. A staged transposed in LDS (sA[k][row],
// row-dim padded 64->68 to keep float4 alignment and spread banks).
// In-place safe: block reads exactly the rows it writes (h) + separate mean buf.

__global__ __launch_bounds__(256) void sage_gemm(
    const float* __restrict__ h, const float* __restrict__ mean,
    const float* __restrict__ Ws, const float* __restrict__ Wn,
    const float* __restrict__ bias, float* __restrict__ out) {
    __shared__ float sA[32][68];
    __shared__ float sW[32][128];

    const int t = threadIdx.x;
    const int rg = t >> 5;   // 0..7 : row group (8 rows each)
    const int cg = t & 31;   // 0..31: col group (4 cols each)
    const int row0 = blockIdx.x * 64;

    float acc[8][4];
#pragma unroll
    for (int i = 0; i < 8; i++)
#pragma unroll
        for (int jj = 0; jj < 4; jj++) acc[i][jj] = 0.f;

    // staging indices (constant across chunks)
    const int sr = t >> 3;        // 0..31 : A-stage row
    const int sk4 = t & 7;        // 0..7  : A-stage k-quad
    int gr0 = row0 + sr;        if (gr0 >= N_NODES) gr0 = N_NODES - 1;
    int gr1 = row0 + 32 + sr;   if (gr1 >= N_NODES) gr1 = N_NODES - 1;

    for (int chunk = 0; chunk < 8; chunk++) {
        const int k0 = (chunk & 3) * 32;
        const float* __restrict__ Asrc = (chunk < 4) ? h : mean;
        const float* __restrict__ Wsrc = (chunk < 4) ? Ws : Wn;

        __syncthreads();
        // stage A chunk (64 rows x 32 k) transposed: 2 float4 loads/thread
        {
            float4 v0 = ((const float4*)(Asrc + (size_t)gr0 * D + k0))[sk4];
            float4 v1 = ((const float4*)(Asrc + (size_t)gr1 * D + k0))[sk4];
            int kb = sk4 * 4;
            sA[kb + 0][sr] = v0.x; sA[kb + 1][sr] = v0.y;
            sA[kb + 2][sr] = v0.z; sA[kb + 3][sr] = v0.w;
            sA[kb + 0][32 + sr] = v1.x; sA[kb + 1][32 + sr] = v1.y;
            sA[kb + 2][32 + sr] = v1.z; sA[kb + 3][32 + sr] = v1.w;
        }
        // stage W chunk (32 k x 128 cols) row-major: 4 float4/thread
#pragma unroll
        for (int i = 0; i < 4; i++) {
            int f = t + i * 256;          // 0..1023
            int kk = f >> 5, c4 = f & 31;
            *((float4*)&sW[kk][c4 * 4]) =
                ((const float4*)(Wsrc + (size_t)(k0 + kk) * D))[c4];
        }
        __syncthreads();

#pragma unroll
        for (int k = 0; k < 32; k++) {
            float4 a0 = *(const float4*)&sA[k][rg * 8];
            float4 a1 = *(const float4*)&sA[k][rg * 8 + 4];
            float4 w  = *(const float4*)&sW[k][cg * 4];
            float ar[8] = {a0.x, a0.y, a0.z, a0.w, a1.x, a1.y, a1.z, a1.w};
#pragma unroll
            for (int rr = 0; rr < 8; rr++) {
                acc[rr][0] += ar[rr] * w.x;
                acc[rr][1] += ar[rr] * w.y;
                acc[rr][2] += ar[rr] * w.z;
                acc[rr][3] += ar[rr] * w.w;
            }
        }
    }

    const float4 bv = ((const float4*)bias)[cg];
#pragma unroll
    for (int rr = 0; rr < 8; rr++) {
        int r = row0 + rg * 8 + rr;
        if (r < N_NODES) {
            float4 o;
            o.x = acc[rr][0] + bv.x;
            o.y = acc[rr][1] + bv.y;
            o.z = acc[rr][2] + bv.z;
            o.w = acc[rr][3] + bv.w;
            ((float4*)(out + (size_t)r * D))[cg] = o;
        }
    }
}

// ---------------- BatchNorm stats + normalize+ReLU ----------------

__global__ void col_stats(const float* __restrict__ h, float* __restrict__ colsum,
                          float* __restrict__ colsumsq) {
    __shared__ float s1[256], s2[256];
    int t = threadIdx.x;
    int j = t & 127, half = t >> 7;
    float s = 0.f, q = 0.f;
    for (int r = blockIdx.x * 2 + half; r < N_NODES; r += gridDim.x * 2) {
        float v = h[(size_t)r * D + j];
        s += v; q += v * v;
    }
    s1[t] = s; s2[t] = q;
    __syncthreads();
    if (t < 128) {
        s = s1[t] + s1[t + 128];
        q = s2[t] + s2[t + 128];
        atomicAdd(&colsum[j], s);
        atomicAdd(&colsumsq[j], q);
    }
}

__global__ void bn_relu(float* __restrict__ h, const float* __restrict__ colsum,
                        const float* __restrict__ colsumsq,
                        const float* __restrict__ gamma, const float* __restrict__ beta) {
    int idx = blockIdx.x * 256 + threadIdx.x;  // over N*D/4 float4s
    if (idx >= N_NODES * (D / 4)) return;
    int c = idx & 31;
    float4 v = ((float4*)h)[idx];
    float4 s = ((const float4*)colsum)[c];
    float4 q = ((const float4*)colsumsq)[c];
    float4 g = ((const float4*)gamma)[c];
    float4 b = ((const float4*)beta)[c];
    const float invN = 1.0f / (float)N_NODES;
    float m, var, sc;
    m = s.x * invN; var = q.x * invN - m * m; sc = rsqrtf(var + BN_EPS) * g.x;
    v.x = fmaxf((v.x - m) * sc + b.x, 0.f);
    m = s.y * invN; var = q.y * invN - m * m; sc = rsqrtf(var + BN_EPS) * g.y;
    v.y = fmaxf((v.y - m) * sc + b.y, 0.f);
    m = s.z * invN; var = q.z * invN - m * m; sc = rsqrtf(var + BN_EPS) * g.z;
    v.z = fmaxf((v.z - m) * sc + b.z, 0.f);
    m = s.w * invN; var = q.w * invN - m * m; sc = rsqrtf(var + BN_EPS) * g.w;
    v.w = fmaxf((v.w - m) * sc + b.w, 0.f);
    ((float4*)h)[idx] = v;
}

// ---------------- launch ----------------

extern "C" void kernel_launch(void* const* d_in, const int* in_sizes, int n_in,
                              void* d_out, int out_size, void* d_ws, size_t ws_size,
                              hipStream_t stream) {
    const float* x   = (const float*)d_in[0];
    const int* src   = (const int*)d_in[1];
    const int* dst   = (const int*)d_in[2];
    const float* Ws0 = (const float*)d_in[3];
    const float* Wn0 = (const float*)d_in[4];
    const float* b0  = (const float*)d_in[5];
    const float* Ws1 = (const float*)d_in[6];
    const float* Wn1 = (const float*)d_in[7];
    const float* b1  = (const float*)d_in[8];
    const float* Ws2 = (const float*)d_in[9];
    const float* Wn2 = (const float*)d_in[10];
    const float* b2  = (const float*)d_in[11];
    const float* g0  = (const float*)d_in[12];
    const float* be0 = (const float*)d_in[13];
    const float* g1  = (const float*)d_in[14];
    const float* be1 = (const float*)d_in[15];

    char* base = (char*)d_ws;
    size_t NND = (size_t)N_NODES * D;
    float* meanbuf = (float*)base;                       // 25.6 MB
    float* bufH    = (float*)(base + NND * 4);           // 25.6 MB
    char* p = base + 2 * NND * 4;
    int* degi    = (int*)p;              p += N_NODES * 4;
    int* offsets = (int*)p;              p += N_NODES * 4;
    int* cursor  = (int*)p;              p += N_NODES * 4;
    int* csr     = (int*)p;              p += (size_t)N_EDGES * 4;
    int* bsum    = (int*)p;              p += 1024;
    float* colsum   = (float*)p;         p += 512;
    float* colsumsq = (float*)p;         p += 512;
    float* inv_deg  = (float*)p;         p += N_NODES * 4;

    const int NB = (N_NODES + 255) / 256;  // 196
    const int EB = (N_EDGES + 255) / 256;  // 3125

    // CSR build (once; reused by all 3 layers)
    hipMemsetAsync(degi, 0, N_NODES * 4, stream);
    count_deg<<<EB, 256, 0, stream>>>(dst, degi);
    calc_inv<<<NB, 256, 0, stream>>>(degi, inv_deg);
    scan1<<<NB, 256, 0, stream>>>(degi, bsum);
    scan2<<<1, 256, 0, stream>>>(bsum, NB);
    scan3<<<NB, 256, 0, stream>>>(degi, bsum, offsets, cursor);
    csr_fill<<<EB, 256, 0, stream>>>(src, dst, cursor, csr);

    const int AGG_B = (N_NODES + 7) / 8;       // 6250
    const int GEMM_B = (N_NODES + 63) / 64;    // 782
    const int EW_B = (N_NODES * (D / 4) + 255) / 256;  // 6250

    // Layer 0: x -> bufH, then BN+ReLU in place
    aggregate<<<AGG_B, 256, 0, stream>>>(x, csr, offsets, degi, inv_deg, meanbuf);
    sage_gemm<<<GEMM_B, 256, 0, stream>>>(x, meanbuf, Ws0, Wn0, b0, bufH);
    hipMemsetAsync(colsum, 0, 1024, stream);  // colsum + colsumsq contiguous
    col_stats<<<256, 256, 0, stream>>>(bufH, colsum, colsumsq);
    bn_relu<<<EW_B, 256, 0, stream>>>(bufH, colsum, colsumsq, g0, be0);

    // Layer 1: bufH -> bufH (in place), BN+ReLU
    aggregate<<<AGG_B, 256, 0, stream>>>(bufH, csr, offsets, degi, inv_deg, meanbuf);
    sage_gemm<<<GEMM_B, 256, 0, stream>>>(bufH, meanbuf, Ws1, Wn1, b1, bufH);
    hipMemsetAsync(colsum, 0, 1024, stream);
    col_stats<<<256, 256, 0, stream>>>(bufH, colsum, colsumsq);
    bn_relu<<<EW_B, 256, 0, stream>>>(bufH, colsum, colsumsq, g1, be1);

    // Layer 2: bufH -> d_out (no BN)
    float* out = (float*)d_out;
    aggregate<<<AGG_B, 256, 0, stream>>>(bufH, csr, offsets, degi, inv_deg, meanbuf);
    sage_gemm<<<GEMM_B, 256, 0, stream>>>(bufH, meanbuf, Ws2, Wn2, b2, out);
}

// Round 3
// 452.507 us; speedup vs baseline: 3.0148x; 1.3984x over previous
//
#include <hip/hip_runtime.h>

#define N_NODES 50000
#define N_EDGES 800000
#define D 128
#define BN_EPS 1e-5f

typedef __attribute__((ext_vector_type(8))) short bf16x8;
typedef __attribute__((ext_vector_type(4))) float f32x4;

// fp32 -> bf16 (RNE), header-free
__device__ inline unsigned short f2bf(float f) {
    unsigned int u = __float_as_uint(f);
    u = (u + 0x7FFF + ((u >> 16) & 1)) >> 16;
    return (unsigned short)u;
}

// ---------------- CSR construction ----------------

__global__ void count_deg(const int* __restrict__ dst, int* __restrict__ degi) {
    int e = blockIdx.x * 256 + threadIdx.x;
    if (e < N_EDGES) atomicAdd(&degi[dst[e]], 1);
}

__global__ void calc_inv(const int* __restrict__ degi, float* __restrict__ inv_deg) {
    int n = blockIdx.x * 256 + threadIdx.x;
    if (n < N_NODES) inv_deg[n] = 1.0f / (float)max(degi[n], 1);
}

__global__ void scan1(const int* __restrict__ degi, int* __restrict__ bsum) {
    __shared__ int s[256];
    int t = threadIdx.x, i = blockIdx.x * 256 + t;
    s[t] = (i < N_NODES) ? degi[i] : 0;
    __syncthreads();
    for (int off = 128; off > 0; off >>= 1) {
        if (t < off) s[t] += s[t + off];
        __syncthreads();
    }
    if (t == 0) bsum[blockIdx.x] = s[0];
}

__global__ void scan2(int* __restrict__ bsum, int nb) {
    __shared__ int s[256];
    int t = threadIdx.x;
    int v = (t < nb) ? bsum[t] : 0;
    s[t] = v;
    __syncthreads();
    for (int off = 1; off < 256; off <<= 1) {
        int x = (t >= off) ? s[t - off] : 0;
        __syncthreads();
        s[t] += x;
        __syncthreads();
    }
    if (t < nb) bsum[t] = s[t] - v;  // exclusive prefix of block sums
}

__global__ void scan3(const int* __restrict__ degi, const int* __restrict__ bsum,
                      int* __restrict__ offsets, int* __restrict__ cursor) {
    __shared__ int s[256];
    int t = threadIdx.x, i = blockIdx.x * 256 + t;
    int v = (i < N_NODES) ? degi[i] : 0;
    s[t] = v;
    __syncthreads();
    for (int off = 1; off < 256; off <<= 1) {
        int x = (t >= off) ? s[t - off] : 0;
        __syncthreads();
        s[t] += x;
        __syncthreads();
    }
    int excl = s[t] - v + bsum[blockIdx.x];
    if (i < N_NODES) { offsets[i] = excl; cursor[i] = excl; }
}

__global__ void csr_fill(const int* __restrict__ src, const int* __restrict__ dst,
                         int* __restrict__ cursor, int* __restrict__ csr) {
    int e = blockIdx.x * 256 + threadIdx.x;
    if (e < N_EDGES) {
        int p = atomicAdd(&cursor[dst[e]], 1);
        csr[p] = src[e];
    }
}

// ---------------- fp32 -> bf16 feature conversion ----------------

__global__ void convert_x(const float* __restrict__ x, unsigned short* __restrict__ x16) {
    int idx = blockIdx.x * 256 + threadIdx.x;  // over N*D/4
    if (idx >= N_NODES * (D / 4)) return;
    float4 v = ((const float4*)x)[idx];
    ushort4 o;
    o.x = f2bf(v.x); o.y = f2bf(v.y); o.z = f2bf(v.z); o.w = f2bf(v.w);
    ((ushort4*)x16)[idx] = o;
}

// ---------------- weight packing into MFMA B-fragment order ----------------
// Wcomb[k][n] (k<128: Ws, else Wn). Fragment: lane l holds B[k0+8*(l>>4)+j][n0+(l&15)],
// j=0..7, stored contiguously so a B-frag is one 16B load.
// Wf layout per layer: [kt(8)][nt(8)][lane(64)][j(8)] bf16 = 32768 elems.

__global__ void pack_w(const float* __restrict__ Ws0, const float* __restrict__ Wn0,
                       const float* __restrict__ Ws1, const float* __restrict__ Wn1,
                       const float* __restrict__ Ws2, const float* __restrict__ Wn2,
                       unsigned short* __restrict__ Wf) {
    int idx = blockIdx.x * 256 + threadIdx.x;  // 3*32768
    if (idx >= 3 * 32768) return;
    int layer = idx >> 15;
    int rem = idx & 32767;
    int kt = rem >> 12;
    int nt = (rem >> 9) & 7;
    int lane = (rem >> 3) & 63;
    int j = rem & 7;
    int k = kt * 32 + (lane >> 4) * 8 + j;
    int n = nt * 16 + (lane & 15);
    const float* Wsrc;
    if (layer == 0) Wsrc = (k < 128) ? Ws0 : Wn0;
    else if (layer == 1) Wsrc = (k < 128) ? Ws1 : Wn1;
    else Wsrc = (k < 128) ? Ws2 : Wn2;
    int kk = k & 127;
    Wf[idx] = f2bf(Wsrc[kk * D + n]);
}

// ---------------- mean aggregation (bf16 gather, fp32 accumulate) ----------------
// 16 nodes per 256-thread block; 16 lanes per node, one 16B (8 bf16) load per lane.

__global__ void aggregate16(const unsigned short* __restrict__ h16,
                            const int* __restrict__ csr, const int* __restrict__ offsets,
                            const int* __restrict__ degi, const float* __restrict__ inv_deg,
                            unsigned short* __restrict__ mean16) {
    int node = blockIdx.x * 16 + (threadIdx.x >> 4);
    if (node >= N_NODES) return;
    int c = threadIdx.x & 15;
    int beg = offsets[node], n = degi[node];
    float a0 = 0.f, a1 = 0.f, a2 = 0.f, a3 = 0.f, a4 = 0.f, a5 = 0.f, a6 = 0.f, a7 = 0.f;
    for (int i = 0; i < n; i++) {
        int s = csr[beg + i];
        uint4 v = *(const uint4*)(h16 + (size_t)s * D + c * 8);
        a0 += __uint_as_float(v.x << 16); a1 += __uint_as_float(v.x & 0xffff0000u);
        a2 += __uint_as_float(v.y << 16); a3 += __uint_as_float(v.y & 0xffff0000u);
        a4 += __uint_as_float(v.z << 16); a5 += __uint_as_float(v.z & 0xffff0000u);
        a6 += __uint_as_float(v.w << 16); a7 += __uint_as_float(v.w & 0xffff0000u);
    }
    float w = inv_deg[node];
    uint4 o;
    o.x = ((unsigned)f2bf(a1 * w) << 16) | f2bf(a0 * w);
    o.y = ((unsigned)f2bf(a3 * w) << 16) | f2bf(a2 * w);
    o.z = ((unsigned)f2bf(a5 * w) << 16) | f2bf(a4 * w);
    o.w = ((unsigned)f2bf(a7 * w) << 16) | f2bf(a6 * w);
    *(uint4*)(mean16 + (size_t)node * D + c * 8) = o;
}

// ---------------- MFMA SAGE GEMM: out = [h|mean]_bf16 @ Wf + b ----------------
// Block = 4 waves; wave w computes rows [blk*64 + w*16, +16) x all 128 cols.
// A-frags straight from global bf16 (row-major, k contiguous -> one 16B load).
// B-frags from pre-packed Wf (one 16B load). No LDS.
// C/D layout (m89-verified): col = lane&15, row = (lane>>4)*4 + reg.

__global__ __launch_bounds__(256) void sage_gemm(
    const unsigned short* __restrict__ h16, const unsigned short* __restrict__ mean16,
    const unsigned short* __restrict__ Wf, const float* __restrict__ bias,
    float* __restrict__ out) {
    const int lane = threadIdx.x & 63;
    const int wave = threadIdx.x >> 6;
    const int m = lane & 15;
    const int quad = lane >> 4;
    const int wrow0 = blockIdx.x * 64 + wave * 16;

    int arow = wrow0 + m;
    if (arow >= N_NODES) arow = N_NODES - 1;

    f32x4 acc[8];
#pragma unroll
    for (int i = 0; i < 8; i++) acc[i] = (f32x4)(0.f);

#pragma unroll
    for (int kt = 0; kt < 8; kt++) {
        const unsigned short* Asrc = (kt < 4) ? h16 : mean16;
        int kof = (kt & 3) * 32 + quad * 8;
        bf16x8 af = *(const bf16x8*)(Asrc + (size_t)arow * D + kof);
#pragma unroll
        for (int nt = 0; nt < 8; nt++) {
            bf16x8 bf = *(const bf16x8*)(Wf + ((kt * 8 + nt) * 64 + lane) * 8);
            acc[nt] = __builtin_amdgcn_mfma_f32_16x16x32_bf16(af, bf, acc[nt], 0, 0, 0);
        }
    }

#pragma unroll
    for (int nt = 0; nt < 8; nt++) {
        int cidx = nt * 16 + m;
        float bv = bias[cidx];
#pragma unroll
        for (int reg = 0; reg < 4; reg++) {
            int r = wrow0 + quad * 4 + reg;
            if (r < N_NODES) out[(size_t)r * D + cidx] = acc[nt][reg] + bv;
        }
    }
}

// ---------------- BatchNorm stats + normalize+ReLU (bf16 out) ----------------

__global__ void col_stats(const float* __restrict__ h, float* __restrict__ colsum,
                          float* __restrict__ colsumsq) {
    __shared__ float s1[256], s2[256];
    int t = threadIdx.x;
    int j = t & 127, half = t >> 7;
    float s = 0.f, q = 0.f;
    for (int r = blockIdx.x * 2 + half; r < N_NODES; r += gridDim.x * 2) {
        float v = h[(size_t)r * D + j];
        s += v; q += v * v;
    }
    s1[t] = s; s2[t] = q;
    __syncthreads();
    if (t < 128) {
        s = s1[t] + s1[t + 128];
        q = s2[t] + s2[t + 128];
        atomicAdd(&colsum[j], s);
        atomicAdd(&colsumsq[j], q);
    }
}

__global__ void bn_relu16(const float* __restrict__ h, unsigned short* __restrict__ h16,
                          const float* __restrict__ colsum, const float* __restrict__ colsumsq,
                          const float* __restrict__ gamma, const float* __restrict__ beta) {
    int idx = blockIdx.x * 256 + threadIdx.x;  // over N*D/4 float4s
    if (idx >= N_NODES * (D / 4)) return;
    int c = idx & 31;
    float4 v = ((const float4*)h)[idx];
    float4 s = ((const float4*)colsum)[c];
    float4 q = ((const float4*)colsumsq)[c];
    float4 g = ((const float4*)gamma)[c];
    float4 b = ((const float4*)beta)[c];
    const float invN = 1.0f / (float)N_NODES;
    float m, var, sc;
    m = s.x * invN; var = q.x * invN - m * m; sc = rsqrtf(var + BN_EPS) * g.x;
    v.x = fmaxf((v.x - m) * sc + b.x, 0.f);
    m = s.y * invN; var = q.y * invN - m * m; sc = rsqrtf(var + BN_EPS) * g.y;
    v.y = fmaxf((v.y - m) * sc + b.y, 0.f);
    m = s.z * invN; var = q.z * invN - m * m; sc = rsqrtf(var + BN_EPS) * g.z;
    v.z = fmaxf((v.z - m) * sc + b.z, 0.f);
    m = s.w * invN; var = q.w * invN - m * m; sc = rsqrtf(var + BN_EPS) * g.w;
    v.w = fmaxf((v.w - m) * sc + b.w, 0.f);
    ushort4 o;
    o.x = f2bf(v.x); o.y = f2bf(v.y); o.z = f2bf(v.z); o.w = f2bf(v.w);
    ((ushort4*)h16)[idx] = o;
}

// ---------------- launch ----------------

extern "C" void kernel_launch(void* const* d_in, const int* in_sizes, int n_in,
                              void* d_out, int out_size, void* d_ws, size_t ws_size,
                              hipStream_t stream) {
    const float* x   = (const float*)d_in[0];
    const int* src   = (const int*)d_in[1];
    const int* dst   = (const int*)d_in[2];
    const float* Ws0 = (const float*)d_in[3];
    const float* Wn0 = (const float*)d_in[4];
    const float* b0  = (const float*)d_in[5];
    const float* Ws1 = (const float*)d_in[6];
    const float* Wn1 = (const float*)d_in[7];
    const float* b1  = (const float*)d_in[8];
    const float* Ws2 = (const float*)d_in[9];
    const float* Wn2 = (const float*)d_in[10];
    const float* b2  = (const float*)d_in[11];
    const float* g0  = (const float*)d_in[12];
    const float* be0 = (const float*)d_in[13];
    const float* g1  = (const float*)d_in[14];
    const float* be1 = (const float*)d_in[15];

    char* base = (char*)d_ws;
    size_t NND = (size_t)N_NODES * D;
    unsigned short* h16buf  = (unsigned short*)base;                 // 12.8 MB (x16, then post-BN h16)
    unsigned short* mean16  = (unsigned short*)(base + NND * 2);     // 12.8 MB
    float* bufF             = (float*)(base + 2 * NND * 2);          // 25.6 MB fp32 GEMM out
    char* p = base + 2 * NND * 2 + NND * 4;
    unsigned short* Wf = (unsigned short*)p;   p += 3 * 32768 * 2;   // 192 KB
    int* degi    = (int*)p;              p += N_NODES * 4;
    int* offsets = (int*)p;              p += N_NODES * 4;
    int* cursor  = (int*)p;              p += N_NODES * 4;
    int* csr     = (int*)p;              p += (size_t)N_EDGES * 4;
    int* bsum    = (int*)p;              p += 1024;
    float* colsum   = (float*)p;         p += 512;
    float* colsumsq = (float*)p;         p += 512;
    float* inv_deg  = (float*)p;         p += N_NODES * 4;

    const int NB = (N_NODES + 255) / 256;  // 196
    const int EB = (N_EDGES + 255) / 256;  // 3125

    // CSR build (once; reused by all 3 layers)
    hipMemsetAsync(degi, 0, N_NODES * 4, stream);
    count_deg<<<EB, 256, 0, stream>>>(dst, degi);
    calc_inv<<<NB, 256, 0, stream>>>(degi, inv_deg);
    scan1<<<NB, 256, 0, stream>>>(degi, bsum);
    scan2<<<1, 256, 0, stream>>>(bsum, NB);
    scan3<<<NB, 256, 0, stream>>>(degi, bsum, offsets, cursor);
    csr_fill<<<EB, 256, 0, stream>>>(src, dst, cursor, csr);

    const int EW_B = (N_NODES * (D / 4) + 255) / 256;  // 6250
    const int AGG_B = (N_NODES + 15) / 16;             // 3125
    const int GEMM_B = (N_NODES + 63) / 64;            // 782

    convert_x<<<EW_B, 256, 0, stream>>>(x, h16buf);
    pack_w<<<(3 * 32768 + 255) / 256, 256, 0, stream>>>(Ws0, Wn0, Ws1, Wn1, Ws2, Wn2, Wf);

    // Layer 0
    aggregate16<<<AGG_B, 256, 0, stream>>>(h16buf, csr, offsets, degi, inv_deg, mean16);
    sage_gemm<<<GEMM_B, 256, 0, stream>>>(h16buf, mean16, Wf, b0, bufF);
    hipMemsetAsync(colsum, 0, 1024, stream);  // colsum + colsumsq contiguous
    col_stats<<<256, 256, 0, stream>>>(bufF, colsum, colsumsq);
    bn_relu16<<<EW_B, 256, 0, stream>>>(bufF, h16buf, colsum, colsumsq, g0, be0);

    // Layer 1
    aggregate16<<<AGG_B, 256, 0, stream>>>(h16buf, csr, offsets, degi, inv_deg, mean16);
    sage_gemm<<<GEMM_B, 256, 0, stream>>>(h16buf, mean16, Wf + 32768, b1, bufF);
    hipMemsetAsync(colsum, 0, 1024, stream);
    col_stats<<<256, 256, 0, stream>>>(bufF, colsum, colsumsq);
    bn_relu16<<<EW_B, 256, 0, stream>>>(bufF, h16buf, colsum, colsumsq, g1, be1);

    // Layer 2 -> d_out (fp32, no BN)
    aggregate16<<<AGG_B, 256, 0, stream>>>(h16buf, csr, offsets, degi, inv_deg, mean16);
    sage_gemm<<<GEMM_B, 256, 0, stream>>>(h16buf, mean16, Wf + 65536, b2, (float*)d_out);
}

// Round 4
// 375.285 us; speedup vs baseline: 3.6352x; 1.2058x over previous
//
#include <hip/hip_runtime.h>

#define N_NODES 50000
#define N_EDGES 800000
#define D 128
#define BN_EPS 1e-5f

#define NBUCK 391        // ceil(N_NODES / 128)
#define BSHIFT 7         // 128 nodes per bucket
#define S1_BLOCKS 256
#define EPB 3125         // edges per histogram/scatter block (256*3125 == 800000)
#define CVT_BLOCKS 6250  // N_NODES*D/4 / 256
#define PACK_BLOCKS 384  // 3*32768 / 256

typedef __attribute__((ext_vector_type(8))) short bf16x8;
typedef __attribute__((ext_vector_type(4))) float f32x4;

// fp32 -> bf16 (RNE)
__device__ inline unsigned short f2bf(float f) {
    unsigned int u = __float_as_uint(f);
    u = (u + 0x7FFF + ((u >> 16) & 1)) >> 16;
    return (unsigned short)u;
}

// ---------------- fused prep: convert_x | edge histogram | pack_w ----------------
// Independent work items packed into one dispatch by blockIdx range.

__global__ void fused_prep(const float* __restrict__ x, unsigned short* __restrict__ x16,
                           const int* __restrict__ dst, int* __restrict__ hist,
                           const float* __restrict__ Ws0, const float* __restrict__ Wn0,
                           const float* __restrict__ Ws1, const float* __restrict__ Wn1,
                           const float* __restrict__ Ws2, const float* __restrict__ Wn2,
                           unsigned short* __restrict__ Wf) {
    __shared__ int lh[NBUCK];
    const int bid = blockIdx.x, t = threadIdx.x;

    if (bid < CVT_BLOCKS) {
        // fp32 -> bf16 feature conversion
        int idx = bid * 256 + t;
        float4 v = ((const float4*)x)[idx];
        ushort4 o;
        o.x = f2bf(v.x); o.y = f2bf(v.y); o.z = f2bf(v.z); o.w = f2bf(v.w);
        ((ushort4*)x16)[idx] = o;
    } else if (bid < CVT_BLOCKS + S1_BLOCKS) {
        // per-block bucket histogram of dst
        int blk = bid - CVT_BLOCKS;
        for (int i = t; i < NBUCK; i += 256) lh[i] = 0;
        __syncthreads();
        int e0 = blk * EPB;
        for (int i = 0; i < 13; i++) {
            int k = t + i * 256;
            if (k < EPB) atomicAdd(&lh[dst[e0 + k] >> BSHIFT], 1);
        }
        __syncthreads();
        for (int i = t; i < NBUCK; i += 256) hist[blk * NBUCK + i] = lh[i];
    } else {
        // pack weights into MFMA B-fragment order:
        // Wf[layer][kt(8)][nt(8)][lane(64)][j(8)], lane l holds
        // B[kt*32 + 8*(l>>4) + j][nt*16 + (l&15)].
        int idx = (bid - (CVT_BLOCKS + S1_BLOCKS)) * 256 + t;
        if (idx < 3 * 32768) {
            int layer = idx >> 15;
            int rem = idx & 32767;
            int kt = rem >> 12;
            int nt = (rem >> 9) & 7;
            int lane = (rem >> 3) & 63;
            int j = rem & 7;
            int k = kt * 32 + (lane >> 4) * 8 + j;
            int n = nt * 16 + (lane & 15);
            const float* Wsrc;
            if (layer == 0) Wsrc = (k < 128) ? Ws0 : Wn0;
            else if (layer == 1) Wsrc = (k < 128) ? Ws1 : Wn1;
            else Wsrc = (k < 128) ? Ws2 : Wn2;
            Wf[idx] = f2bf(Wsrc[(k & 127) * D + n]);
        }
    }
}

// ---------------- S2a: per-bucket exclusive prefix over blocks ----------------

__global__ void s2a(int* __restrict__ hist, int* __restrict__ bucketTotal) {
    __shared__ int s[S1_BLOCKS];
    int b = blockIdx.x, t = threadIdx.x;
    int v = hist[t * NBUCK + b];
    s[t] = v;
    __syncthreads();
    for (int off = 1; off < S1_BLOCKS; off <<= 1) {
        int x = (t >= off) ? s[t - off] : 0;
        __syncthreads();
        s[t] += x;
        __syncthreads();
    }
    hist[t * NBUCK + b] = s[t] - v;  // exclusive within-bucket prefix
    if (t == S1_BLOCKS - 1) bucketTotal[b] = s[t];
}

// ---------------- S2b: exclusive scan of bucket totals ----------------

__global__ void s2b(const int* __restrict__ bucketTotal, int* __restrict__ bucketStart) {
    __shared__ int s[512];
    int t = threadIdx.x;
    int v = (t < NBUCK) ? bucketTotal[t] : 0;
    s[t] = v;
    __syncthreads();
    for (int off = 1; off < 512; off <<= 1) {
        int x = (t >= off) ? s[t - off] : 0;
        __syncthreads();
        s[t] += x;
        __syncthreads();
    }
    if (t <= NBUCK) bucketStart[t] = s[t] - v;  // [NBUCK] = N_EDGES sentinel
}

// ---------------- S3: scatter packed records, bucket-grouped ----------------
// rec = (dst&127)<<16 | src. Each (block,bucket) slot range is consecutive and
// block-exclusive -> stores write-combine in that XCD's L2 (no line thrash).

__global__ void s3_scatter(const int* __restrict__ src, const int* __restrict__ dst,
                           const int* __restrict__ hist, const int* __restrict__ bucketStart,
                           unsigned int* __restrict__ rec) {
    __shared__ int base[NBUCK];
    int blk = blockIdx.x, t = threadIdx.x;
    for (int i = t; i < NBUCK; i += 256)
        base[i] = bucketStart[i] + hist[blk * NBUCK + i];
    __syncthreads();
    int e0 = blk * EPB;
    for (int i = 0; i < 13; i++) {
        int k = t + i * 256;
        if (k < EPB) {
            int e = e0 + k;
            int d = dst[e];
            int p = atomicAdd(&base[d >> BSHIFT], 1);
            rec[p] = ((unsigned)(d & 127) << 16) | (unsigned)src[e];
        }
    }
}

// ---------------- S4: per-bucket counting sort -> CSR + degrees ----------------

__global__ void s4_build(const unsigned int* __restrict__ rec, const int* __restrict__ bucketStart,
                         unsigned short* __restrict__ csr, int* __restrict__ degi,
                         int* __restrict__ offsets, float* __restrict__ inv_deg) {
    __shared__ int lh[128];
    __shared__ int ls[128];
    __shared__ int lcur[128];
    int b = blockIdx.x, t = threadIdx.x;
    int start = bucketStart[b], end = bucketStart[b + 1];

    if (t < 128) lh[t] = 0;
    __syncthreads();
    for (int e = start + t; e < end; e += 256)
        atomicAdd(&lh[rec[e] >> 16], 1);
    __syncthreads();

    int v = 0;
    if (t < 128) { v = lh[t]; ls[t] = v; }
    __syncthreads();
    for (int off = 1; off < 128; off <<= 1) {
        int x = 0;
        if (t < 128 && t >= off) x = ls[t - off];
        __syncthreads();
        if (t < 128) ls[t] += x;
        __syncthreads();
    }

    int node0 = b << BSHIFT;
    if (t < 128) {
        int excl = ls[t] - v;
        lcur[t] = start + excl;
        int node = node0 + t;
        if (node < N_NODES) {
            degi[node] = v;
            offsets[node] = start + excl;
            inv_deg[node] = 1.0f / (float)max(v, 1);
        }
    }
    __syncthreads();
    for (int e = start + t; e < end; e += 256) {
        unsigned r = rec[e];
        int p = atomicAdd(&lcur[r >> 16], 1);
        csr[p] = (unsigned short)(r & 0xFFFFu);
    }
}

// ---------------- mean aggregation (bf16 gather, fp32 accumulate) ----------------
// 16 nodes per 256-thread block; 16 lanes per node, one 16B (8 bf16) load per lane.
// Block 0 also zeroes the 256-float BN stats buffer (consumed 2 dispatches later).

__global__ void aggregate16(const unsigned short* __restrict__ h16,
                            const unsigned short* __restrict__ csr, const int* __restrict__ offsets,
                            const int* __restrict__ degi, const float* __restrict__ inv_deg,
                            unsigned short* __restrict__ mean16, float* __restrict__ stats) {
    if (blockIdx.x == 0) stats[threadIdx.x] = 0.f;
    int node = blockIdx.x * 16 + (threadIdx.x >> 4);
    if (node >= N_NODES) return;
    int c = threadIdx.x & 15;
    int beg = offsets[node], n = degi[node];
    float a0 = 0.f, a1 = 0.f, a2 = 0.f, a3 = 0.f, a4 = 0.f, a5 = 0.f, a6 = 0.f, a7 = 0.f;
    for (int i = 0; i < n; i++) {
        int s = csr[beg + i];
        uint4 v = *(const uint4*)(h16 + (size_t)s * D + c * 8);
        a0 += __uint_as_float(v.x << 16); a1 += __uint_as_float(v.x & 0xffff0000u);
        a2 += __uint_as_float(v.y << 16); a3 += __uint_as_float(v.y & 0xffff0000u);
        a4 += __uint_as_float(v.z << 16); a5 += __uint_as_float(v.z & 0xffff0000u);
        a6 += __uint_as_float(v.w << 16); a7 += __uint_as_float(v.w & 0xffff0000u);
    }
    float w = inv_deg[node];
    uint4 o;
    o.x = ((unsigned)f2bf(a1 * w) << 16) | f2bf(a0 * w);
    o.y = ((unsigned)f2bf(a3 * w) << 16) | f2bf(a2 * w);
    o.z = ((unsigned)f2bf(a5 * w) << 16) | f2bf(a4 * w);
    o.w = ((unsigned)f2bf(a7 * w) << 16) | f2bf(a6 * w);
    *(uint4*)(mean16 + (size_t)node * D + c * 8) = o;
}

// ---------------- MFMA SAGE GEMM: out = [h|mean]_bf16 @ Wf + b ----------------
// C/D layout (m89-verified): col = lane&15, row = (lane>>4)*4 + reg.

__global__ __launch_bounds__(256) void sage_gemm(
    const unsigned short* __restrict__ h16, const unsigned short* __restrict__ mean16,
    const unsigned short* __restrict__ Wf, const float* __restrict__ bias,
    float* __restrict__ out) {
    const int lane = threadIdx.x & 63;
    const int wave = threadIdx.x >> 6;
    const int m = lane & 15;
    const int quad = lane >> 4;
    const int wrow0 = blockIdx.x * 64 + wave * 16;

    int arow = wrow0 + m;
    if (arow >= N_NODES) arow = N_NODES - 1;

    f32x4 acc[8];
#pragma unroll
    for (int i = 0; i < 8; i++) acc[i] = (f32x4)(0.f);

#pragma unroll
    for (int kt = 0; kt < 8; kt++) {
        const unsigned short* Asrc = (kt < 4) ? h16 : mean16;
        int kof = (kt & 3) * 32 + quad * 8;
        bf16x8 af = *(const bf16x8*)(Asrc + (size_t)arow * D + kof);
#pragma unroll
        for (int nt = 0; nt < 8; nt++) {
            bf16x8 bf = *(const bf16x8*)(Wf + ((kt * 8 + nt) * 64 + lane) * 8);
            acc[nt] = __builtin_amdgcn_mfma_f32_16x16x32_bf16(af, bf, acc[nt], 0, 0, 0);
        }
    }

#pragma unroll
    for (int nt = 0; nt < 8; nt++) {
        int cidx = nt * 16 + m;
        float bv = bias[cidx];
#pragma unroll
        for (int reg = 0; reg < 4; reg++) {
            int r = wrow0 + quad * 4 + reg;
            if (r < N_NODES) out[(size_t)r * D + cidx] = acc[nt][reg] + bv;
        }
    }
}

// ---------------- BatchNorm stats + normalize+ReLU (bf16 out) ----------------

__global__ void col_stats(const float* __restrict__ h, float* __restrict__ stats) {
    __shared__ float s1[256], s2[256];
    int t = threadIdx.x;
    int j = t & 127, half = t >> 7;
    float s = 0.f, q = 0.f;
    for (int r = blockIdx.x * 2 + half; r < N_NODES; r += gridDim.x * 2) {
        float v = h[(size_t)r * D + j];
        s += v; q += v * v;
    }
    s1[t] = s; s2[t] = q;
    __syncthreads();
    if (t < 128) {
        s = s1[t] + s1[t + 128];
        q = s2[t] + s2[t + 128];
        atomicAdd(&stats[j], s);
        atomicAdd(&stats[128 + j], q);
    }
}

__global__ void bn_relu16(const float* __restrict__ h, unsigned short* __restrict__ h16,
                          const float* __restrict__ stats,
                          const float* __restrict__ gamma, const float* __restrict__ beta) {
    int idx = blockIdx.x * 256 + threadIdx.x;  // over N*D/4 float4s
    if (idx >= N_NODES * (D / 4)) return;
    int c = idx & 31;
    float4 v = ((const float4*)h)[idx];
    float4 s = ((const float4*)stats)[c];
    float4 q = ((const float4*)stats)[32 + c];
    float4 g = ((const float4*)gamma)[c];
    float4 b = ((const float4*)beta)[c];
    const float invN = 1.0f / (float)N_NODES;
    float m, var, sc;
    m = s.x * invN; var = q.x * invN - m * m; sc = rsqrtf(var + BN_EPS) * g.x;
    v.x = fmaxf((v.x - m) * sc + b.x, 0.f);
    m = s.y * invN; var = q.y * invN - m * m; sc = rsqrtf(var + BN_EPS) * g.y;
    v.y = fmaxf((v.y - m) * sc + b.y, 0.f);
    m = s.z * invN; var = q.z * invN - m * m; sc = rsqrtf(var + BN_EPS) * g.z;
    v.z = fmaxf((v.z - m) * sc + b.z, 0.f);
    m = s.w * invN; var = q.w * invN - m * m; sc = rsqrtf(var + BN_EPS) * g.w;
    v.w = fmaxf((v.w - m) * sc + b.w, 0.f);
    ushort4 o;
    o.x = f2bf(v.x); o.y = f2bf(v.y); o.z = f2bf(v.z); o.w = f2bf(v.w);
    ((ushort4*)h16)[idx] = o;
}

// ---------------- launch ----------------

extern "C" void kernel_launch(void* const* d_in, const int* in_sizes, int n_in,
                              void* d_out, int out_size, void* d_ws, size_t ws_size,
                              hipStream_t stream) {
    const float* x   = (const float*)d_in[0];
    const int* src   = (const int*)d_in[1];
    const int* dst   = (const int*)d_in[2];
    const float* Ws0 = (const float*)d_in[3];
    const float* Wn0 = (const float*)d_in[4];
    const float* b0  = (const float*)d_in[5];
    const float* Ws1 = (const float*)d_in[6];
    const float* Wn1 = (const float*)d_in[7];
    const float* b1  = (const float*)d_in[8];
    const float* Ws2 = (const float*)d_in[9];
    const float* Wn2 = (const float*)d_in[10];
    const float* b2  = (const float*)d_in[11];
    const float* g0  = (const float*)d_in[12];
    const float* be0 = (const float*)d_in[13];
    const float* g1  = (const float*)d_in[14];
    const float* be1 = (const float*)d_in[15];

    char* base = (char*)d_ws;
    size_t NND = (size_t)N_NODES * D;
    unsigned short* h16buf = (unsigned short*)base;               // 12.8 MB
    unsigned short* mean16 = (unsigned short*)(base + NND * 2);   // 12.8 MB
    float* bufF            = (float*)(base + 2 * NND * 2);        // 25.6 MB
    char* p = base + 2 * NND * 2 + NND * 4;
    unsigned short* Wf = (unsigned short*)p;  p += 3 * 32768 * 2;          // 192 KB
    int* hist          = (int*)p;             p += (size_t)S1_BLOCKS * NBUCK * 4;  // 400 KB
    int* bucketTotal   = (int*)p;             p += 1568;
    int* bucketStart   = (int*)p;             p += 1568;
    unsigned int* rec  = (unsigned int*)p;    p += (size_t)N_EDGES * 4;    // 3.2 MB
    unsigned short* csr = (unsigned short*)p; p += (size_t)N_EDGES * 2;    // 1.6 MB
    int* degi    = (int*)p;                   p += N_NODES * 4;
    int* offsets = (int*)p;                   p += N_NODES * 4;
    float* inv_deg = (float*)p;               p += N_NODES * 4;
    float* stats   = (float*)p;               p += 1024;  // colsum[128] | colsumsq[128]

    // prep: feature convert + edge histogram + weight pack (one dispatch)
    fused_prep<<<CVT_BLOCKS + S1_BLOCKS + PACK_BLOCKS, 256, 0, stream>>>(
        x, h16buf, dst, hist, Ws0, Wn0, Ws1, Wn1, Ws2, Wn2, Wf);
    s2a<<<NBUCK, 256, 0, stream>>>(hist, bucketTotal);
    s2b<<<1, 512, 0, stream>>>(bucketTotal, bucketStart);
    s3_scatter<<<S1_BLOCKS, 256, 0, stream>>>(src, dst, hist, bucketStart, rec);
    s4_build<<<NBUCK, 256, 0, stream>>>(rec, bucketStart, csr, degi, offsets, inv_deg);

    const int AGG_B = (N_NODES + 15) / 16;   // 3125
    const int GEMM_B = (N_NODES + 63) / 64;  // 782
    const int EW_B = (N_NODES * (D / 4) + 255) / 256;  // 6250

    // Layer 0
    aggregate16<<<AGG_B, 256, 0, stream>>>(h16buf, csr, offsets, degi, inv_deg, mean16, stats);
    sage_gemm<<<GEMM_B, 256, 0, stream>>>(h16buf, mean16, Wf, b0, bufF);
    col_stats<<<256, 256, 0, stream>>>(bufF, stats);
    bn_relu16<<<EW_B, 256, 0, stream>>>(bufF, h16buf, stats, g0, be0);

    // Layer 1
    aggregate16<<<AGG_B, 256, 0, stream>>>(h16buf, csr, offsets, degi, inv_deg, mean16, stats);
    sage_gemm<<<GEMM_B, 256, 0, stream>>>(h16buf, mean16, Wf + 32768, b1, bufF);
    col_stats<<<256, 256, 0, stream>>>(bufF, stats);
    bn_relu16<<<EW_B, 256, 0, stream>>>(bufF, h16buf, stats, g1, be1);

    // Layer 2 -> d_out (fp32, no BN)
    aggregate16<<<AGG_B, 256, 0, stream>>>(h16buf, csr, offsets, degi, inv_deg, mean16, stats);
    sage_gemm<<<GEMM_B, 256, 0, stream>>>(h16buf, mean16, Wf + 65536, b2, (float*)d_out);
}